// Round 9
// baseline (141.392 us; speedup 1.0000x reference)
//
#include <hip/hip_runtime.h>
#include <hip/hip_bf16.h>
#include <math.h>

#define NTOK 8192     // B*L
#define DIM  1024     // D
#define VDIM 32       // V
#define KCODES 4096   // K

// hp is pre-scaled by 2*log2(e): score MFMA yields c*s, softmax weight = exp2(c*s) = e^{2s}.
#define SC 2.8853900817779268f

typedef __attribute__((ext_vector_type(8))) short short8;
typedef __attribute__((ext_vector_type(4))) float f32x4;

// MFMA16(A,B,C): D[row 4q+r = A-row][col m = B-row]; A-frag lane(q,m) holds
// A[m][k=q*8+j], B-frag lane(q,m) holds B[n=m][k=q*8+j]. (verified R2-R8)
#define MFMA16(A,B,C) __builtin_amdgcn_mfma_f32_16x16x32_bf16(A, B, C, 0, 0, 0)

__device__ __forceinline__ unsigned short f2bf(float x) {
    unsigned u = __builtin_bit_cast(unsigned, x);
    u += 0x7FFF + ((u >> 16) & 1);              // RTNE (finite inputs only)
    return (unsigned short)(u >> 16);
}
__device__ __forceinline__ float bf2f(unsigned short b) {
    unsigned u = ((unsigned)b) << 16;
    return __builtin_bit_cast(float, u);
}
__device__ __forceinline__ float fexp2(float x) {
#if __has_builtin(__builtin_amdgcn_exp2f)
    return __builtin_amdgcn_exp2f(x);
#else
    return __expf(0.6931471805599453f * x);
#endif
}

struct U4 { unsigned x, y, z, w; };

// split 8 fp32 -> bf16 hi/lo fragments (RTNE; element j of frag = p[j])
__device__ __forceinline__ void split8(const float* p, short8* H, short8* L) {
    unsigned hh[4], ll[4];
    #pragma unroll
    for (int i = 0; i < 4; ++i) {
        unsigned short a = f2bf(p[2 * i]);
        unsigned short b = f2bf(p[2 * i + 1]);
        hh[i] = (unsigned)a | ((unsigned)b << 16);
        unsigned short la = f2bf(p[2 * i] - bf2f(a));
        unsigned short lb = f2bf(p[2 * i + 1] - bf2f(b));
        ll[i] = (unsigned)la | ((unsigned)lb << 16);
    }
    U4 uh = {hh[0], hh[1], hh[2], hh[3]};
    U4 ul = {ll[0], ll[1], ll[2], ll[3]};
    *H = __builtin_bit_cast(short8, uh);
    *L = __builtin_bit_cast(short8, ul);
}

// pack 8 positive fp32 -> bf16 (round-half-up) via v_perm: 8 adds + 4 perms
__device__ __forceinline__ short8 pack8(const float* p) {
    unsigned u[8];
    #pragma unroll
    for (int j = 0; j < 8; ++j) u[j] = __builtin_bit_cast(unsigned, p[j]) + 0x8000u;
    U4 uh;
    uh.x = __builtin_amdgcn_perm(u[1], u[0], 0x07060302);
    uh.y = __builtin_amdgcn_perm(u[3], u[2], 0x07060302);
    uh.z = __builtin_amdgcn_perm(u[5], u[4], 0x07060302);
    uh.w = __builtin_amdgcn_perm(u[7], u[6], 0x07060302);
    return __builtin_bit_cast(short8, uh);
}

// LDS chunk swizzle for the E tile (row pad 40 u16 + XOR'd 16B chunk index):
// spreads the sigma-permuted b128 reads across bank groups.
__device__ __forceinline__ int lsw(int row, int j) {
    int s = ((row >> 1) ^ (row >> 3)) & 3;
    return row * 40 + ((j ^ s) * 8);
}

// ---------------------------------------------------------------------------
// ws layout: u16 region then f32 region
// ---------------------------------------------------------------------------
#define OFS_E_HI   0          // E  [4096][32]
#define OFS_E_LO   131072
#define OFS_ET_HI  262144     // Et [32][4096] (hi only; PV drops the lo term)
#define OFS_WP_HI  393216     // Wp [32][1024]
#define OFS_WP_LO  425984
#define OFS_WPI_HI 458752     // Wpi [1024][32]
#define OFS_WPI_LO 491520
#define OFS_HP_HI  524288     // hp  [8192][32] (scaled by SC)
#define OFS_HP_LO  786432
#define F32_BASE   1048576    // u16 units -> float* fbase
#define NSPLIT 16
#define FOFS_HVP 0            // [16][8192][32] fp32 partial hv
#define FOFS_LP  4194304     // [16][8192]
#define FOFS_AMP 4325376     // [16][8192]
#define FOFS_AIP 4456448     // [16][8192] (int)

// ---------------------------------------------------------------------------
// k_prep: normalize emb -> E hi/lo + Et hi (coalesced via LDS transpose);
// split Wp/Wpi; vq_loss = 0.
// ---------------------------------------------------------------------------
__global__ __launch_bounds__(256) void k_prep(const float* __restrict__ emb,
                                              const float* __restrict__ Wp,
                                              const float* __restrict__ Wpi,
                                              unsigned short* __restrict__ W,
                                              float* __restrict__ loss_out) {
    __shared__ __align__(16) unsigned short Th[32][72];
    int bid = blockIdx.x, tid = threadIdx.x;
    if (bid < 64) {                       // 64 codes per block
        int cb = bid * 64;
        int c = tid >> 2, s = tid & 3;    // code-local, v-quarter
        const float* src = emb + (size_t)(cb + c) * VDIM + s * 8;
        float4 a = *(const float4*)src;
        float4 b = *(const float4*)(src + 4);
        float ps = a.x*a.x + a.y*a.y + a.z*a.z + a.w*a.w
                 + b.x*b.x + b.y*b.y + b.z*b.z + b.w*b.w;
        ps += __shfl_xor(ps, 1);
        ps += __shfl_xor(ps, 2);
        float inv = 1.0f / sqrtf(ps);
        float vals[8] = {a.x*inv, a.y*inv, a.z*inv, a.w*inv,
                         b.x*inv, b.y*inv, b.z*inv, b.w*inv};
        short8 H, L;
        split8(vals, &H, &L);
        *(short8*)(W + OFS_E_HI + (size_t)(cb + c) * VDIM + s * 8) = H;
        *(short8*)(W + OFS_E_LO + (size_t)(cb + c) * VDIM + s * 8) = L;
        #pragma unroll
        for (int j = 0; j < 8; ++j) Th[s * 8 + j][c] = f2bf(vals[j]);
        __syncthreads();
        int row = tid >> 3, seg = tid & 7;
        *(short8*)(W + OFS_ET_HI + (size_t)row * KCODES + cb + seg * 8) =
            *(const short8*)&Th[row][seg * 8];
        if (bid == 0 && tid == 0) loss_out[0] = 0.0f;
    } else if (bid < 80) {                // Wp split: 16 blocks x 2048
        int i0 = (bid - 64) * 2048 + tid * 8;
        float4 a = *(const float4*)(Wp + i0);
        float4 b = *(const float4*)(Wp + i0 + 4);
        float vals[8] = {a.x, a.y, a.z, a.w, b.x, b.y, b.z, b.w};
        short8 H, L;
        split8(vals, &H, &L);
        *(short8*)(W + OFS_WP_HI + i0) = H;
        *(short8*)(W + OFS_WP_LO + i0) = L;
    } else {                              // Wpi split: 16 blocks x 2048
        int i0 = (bid - 80) * 2048 + tid * 8;
        float4 a = *(const float4*)(Wpi + i0);
        float4 b = *(const float4*)(Wpi + i0 + 4);
        float vals[8] = {a.x, a.y, a.z, a.w, b.x, b.y, b.z, b.w};
        short8 H, L;
        split8(vals, &H, &L);
        *(short8*)(W + OFS_WPI_HI + i0) = H;
        *(short8*)(W + OFS_WPI_LO + i0) = L;
    }
}

// ---------------------------------------------------------------------------
// k_proj: hp = h @ Wp^T + bp, L2-normalize, scale by SC, write bf16 hi/lo.
// 512 blocks x 256 threads (4 waves); 16 tokens/block; wave = 256-wide k-slice.
// ---------------------------------------------------------------------------
__global__ __launch_bounds__(256) void k_proj(const float* __restrict__ h,
                                              const unsigned short* __restrict__ W,
                                              const float* __restrict__ bp,
                                              unsigned short* __restrict__ hp_hi,
                                              unsigned short* __restrict__ hp_lo) {
    __shared__ __align__(16) float red[4][16][36];
    const unsigned short* Wp_hi = W + OFS_WP_HI;
    const unsigned short* Wp_lo = W + OFS_WP_LO;
    int tid = threadIdx.x;
    int w = tid >> 6, l = tid & 63, q = l >> 4, m = l & 15;
    int tok0 = blockIdx.x * 16;
    const f32x4 zero4 = {0.f, 0.f, 0.f, 0.f};
    f32x4 acc0 = zero4, acc1 = zero4;
    const float* hb = h + (size_t)(tok0 + m) * DIM + w * 256 + q * 8;
    const unsigned short* w0h = Wp_hi + (size_t)m * DIM + w * 256 + q * 8;
    const unsigned short* w0l = Wp_lo + (size_t)m * DIM + w * 256 + q * 8;
    const unsigned short* w1h = w0h + (size_t)16 * DIM;
    const unsigned short* w1l = w0l + (size_t)16 * DIM;
    #pragma unroll
    for (int c = 0; c < 8; ++c) {
        float4 a = *(const float4*)(hb + c * 32);
        float4 b = *(const float4*)(hb + c * 32 + 4);
        float va[8] = {a.x, a.y, a.z, a.w, b.x, b.y, b.z, b.w};
        short8 Bh, Bl;
        split8(va, &Bh, &Bl);
        short8 A0h = *(const short8*)(w0h + c * 32);
        short8 A0l = *(const short8*)(w0l + c * 32);
        short8 A1h = *(const short8*)(w1h + c * 32);
        short8 A1l = *(const short8*)(w1l + c * 32);
        acc0 = MFMA16(A0l, Bl, acc0); acc0 = MFMA16(A0l, Bh, acc0);
        acc0 = MFMA16(A0h, Bl, acc0); acc0 = MFMA16(A0h, Bh, acc0);
        acc1 = MFMA16(A1l, Bl, acc1); acc1 = MFMA16(A1l, Bh, acc1);
        acc1 = MFMA16(A1h, Bl, acc1); acc1 = MFMA16(A1h, Bh, acc1);
    }
    *(f32x4*)&red[w][m][4 * q]      = acc0;   // v = 4q+r, token m
    *(f32x4*)&red[w][m][16 + 4 * q] = acc1;
    __syncthreads();
    #pragma unroll
    for (int half = 0; half < 2; ++half) {
        int t = (tid >> 5) + half * 8, v = tid & 31;
        float s = bp[v];
        #pragma unroll
        for (int j = 0; j < 4; ++j) s += red[j][t][v];
        float sq = s * s;
        #pragma unroll
        for (int off = 1; off < 32; off <<= 1) sq += __shfl_xor(sq, off);
        float nv = s * (SC / sqrtf(sq));
        unsigned short hb2 = f2bf(nv);
        size_t idx = (size_t)(tok0 + t) * VDIM + v;
        hp_hi[idx] = hb2;
        hp_lo[idx] = f2bf(nv - bf2f(hb2));
    }
}

// ---------------------------------------------------------------------------
// k_vq: scores (3-product split fp32) -> exp2 -> argmax -> P@E^T (hi-only).
// 1024 blocks x 128 threads (2 waves, launch_bounds(128,2): 4 blocks/CU,
// 2 waves/SIMD). block = 128 tokens x 256-code slice (sp = bid&15); wave =
// FOUR independent 16-token tiles (ILP-4) sharing every E/Et fragment ->
// 32 MFMAs per fragment-load set, 4 interleaved dependency chains.
// E hi/lo double-buffered through LDS in 64-code tiles (20 KB); Et
// register-prefetched one chunk ahead.
// ---------------------------------------------------------------------------
__global__ __launch_bounds__(128, 2) void k_vq(const unsigned short* __restrict__ W,
                                               float* __restrict__ hvp,
                                               float* __restrict__ lp,
                                               float* __restrict__ amp,
                                               int* __restrict__ aip) {
    __shared__ __align__(16) unsigned short Eh[2][64 * 40];   // 20 KB total
    __shared__ __align__(16) unsigned short El[2][64 * 40];

    const unsigned short* E_hi  = W + OFS_E_HI;
    const unsigned short* E_lo  = W + OFS_E_LO;
    const unsigned short* Et_hi = W + OFS_ET_HI;
    const unsigned short* hp_hi = W + OFS_HP_HI;
    const unsigned short* hp_lo = W + OFS_HP_LO;

    int tid = threadIdx.x;
    int w = tid >> 6, l = tid & 63, q = l >> 4, m = l & 15;
    int tg = blockIdx.x >> 4, sp = blockIdx.x & 15;
    int tok0 = tg * 128 + w * 64;            // wave's 64 tokens (4 tiles)
    int cb0 = sp * 256;                      // 256-code slice
    int sig = ((m & 12) << 1) | (m & 3);     // sigma(m) = 8*(m>>2)+(m&3)
    const f32x4 zero4 = {0.f, 0.f, 0.f, 0.f};

    // staging: 64 codes * 4 chunk16 = 256 16B-chunks / 128 threads = 2 each
    int cs = tid >> 1, js = tid & 1;
    int ldA = lsw(cs, js), ldB = lsw(cs, js + 2);
    size_t gA = (size_t)cs * VDIM + js * 8;
    size_t gB = gA + 16;

    size_t h0 = (size_t)(tok0 + m) * VDIM + q * 8;
    short8 hph[4], hpl[4];
    #pragma unroll
    for (int tl = 0; tl < 4; ++tl) {
        hph[tl] = *(const short8*)(hp_hi + h0 + tl * 16 * VDIM);
        hpl[tl] = *(const short8*)(hp_lo + h0 + tl * 16 * VDIM);
    }

    // prologue: stage tile 0 into buf 0
    {
        size_t tb = (size_t)cb0 * VDIM;
        short8 a0 = *(const short8*)(E_hi + tb + gA);
        short8 a1 = *(const short8*)(E_hi + tb + gB);
        short8 b0 = *(const short8*)(E_lo + tb + gA);
        short8 b1 = *(const short8*)(E_lo + tb + gB);
        *(short8*)&Eh[0][ldA] = a0;
        *(short8*)&Eh[0][ldB] = a1;
        *(short8*)&El[0][ldA] = b0;
        *(short8*)&El[0][ldB] = b1;
    }
    __syncthreads();

    f32x4 hv0[4], hv1[4];
    float ls[4], am[4];
    int ai[4];
    #pragma unroll
    for (int tl = 0; tl < 4; ++tl) {
        hv0[tl] = zero4; hv1[tl] = zero4;
        ls[tl] = 0.f; am[tl] = -1e30f; ai[tl] = 0;
    }

    // Et prefetch for chunk 0
    size_t tA = (size_t)sig * KCODES + cb0 + q * 8;
    short8 T0h = *(const short8*)(Et_hi + tA);
    short8 T1h = *(const short8*)(Et_hi + tA + (size_t)4 * KCODES);

    #pragma unroll 1
    for (int t = 0; t < 4; ++t) {            // 4 LDS tiles of 64 codes
        int buf = t & 1;
        short8 sa0, sa1, sb0, sb1;
        if (t < 3) {                         // issue next tile's staging loads
            size_t tb = (size_t)(cb0 + (t + 1) * 64) * VDIM;
            sa0 = *(const short8*)(E_hi + tb + gA);
            sa1 = *(const short8*)(E_hi + tb + gB);
            sb0 = *(const short8*)(E_lo + tb + gA);
            sb1 = *(const short8*)(E_lo + tb + gB);
        }
        #pragma unroll
        for (int cc = 0; cc < 2; ++cc) {     // 2 chunks of 32 codes
            int cbase = cb0 + t * 64 + cc * 32;
            // prefetch Et for next chunk (tail reads in-bounds unused ws)
            size_t tN = (size_t)sig * KCODES + (cbase + 32) + q * 8;
            short8 nT0h = *(const short8*)(Et_hi + tN);
            short8 nT1h = *(const short8*)(Et_hi + tN + (size_t)4 * KCODES);
            // E fragments from LDS (swizzled) — shared by all four token tiles
            int r0 = cc * 32 + sig;
            short8 E0h = *(const short8*)&Eh[buf][lsw(r0, q)];
            short8 E0l = *(const short8*)&El[buf][lsw(r0, q)];
            short8 E1h = *(const short8*)&Eh[buf][lsw(r0 + 4, q)];
            short8 E1l = *(const short8*)&El[buf][lsw(r0 + 4, q)];
            int lbase = cbase + 8 * q;       // lane's codes: lbase+j, j=0..7

            #pragma unroll
            for (int tl = 0; tl < 4; ++tl) { // 4 interleaved token tiles
                f32x4 s0 = MFMA16(E0h, hpl[tl], zero4);
                s0 = MFMA16(E0l, hph[tl], s0);
                s0 = MFMA16(E0h, hph[tl], s0);
                f32x4 s1 = MFMA16(E1h, hpl[tl], zero4);
                s1 = MFMA16(E1l, hph[tl], s1);
                s1 = MFMA16(E1h, hph[tl], s1);
                float p[8];
                #pragma unroll
                for (int r = 0; r < 4; ++r) {
                    float sv = s0[r];
                    if (sv > am[tl]) { am[tl] = sv; ai[tl] = lbase + r; }
                    p[r] = fexp2(sv);
                    sv = s1[r];
                    if (sv > am[tl]) { am[tl] = sv; ai[tl] = lbase + 4 + r; }
                    p[4 + r] = fexp2(sv);
                }
                ls[tl] += ((p[0] + p[1]) + (p[2] + p[3]))
                        + ((p[4] + p[5]) + (p[6] + p[7]));
                short8 Ph = pack8(p);
                hv0[tl] = MFMA16(T0h, Ph, hv0[tl]);  // v = 8q+r,   token m
                hv1[tl] = MFMA16(T1h, Ph, hv1[tl]);  // v = 8q+4+r, token m
            }
            T0h = nT0h; T1h = nT1h;
        }
        if (t < 3) {
            int nb = buf ^ 1;
            *(short8*)&Eh[nb][ldA] = sa0;
            *(short8*)&Eh[nb][ldB] = sa1;
            *(short8*)&El[nb][ldA] = sb0;
            *(short8*)&El[nb][ldB] = sb1;
            __syncthreads();
        }
    }

    // cross-q reduce (lane bits 4,5 share token column m)
    #pragma unroll
    for (int tl = 0; tl < 4; ++tl) {
        #pragma unroll
        for (int off = 16; off <= 32; off <<= 1) {
            ls[tl] += __shfl_xor(ls[tl], off);
            float a2 = __shfl_xor(am[tl], off);
            int   i2 = __shfl_xor(ai[tl], off);
            if (a2 > am[tl] || (a2 == am[tl] && i2 < ai[tl])) { am[tl] = a2; ai[tl] = i2; }
        }
    }
    size_t gtok = (size_t)sp * NTOK + tok0;
    if (q == 0) {
        #pragma unroll
        for (int tl = 0; tl < 4; ++tl) {
            lp[gtok + tl * 16 + m] = ls[tl];
            amp[gtok + tl * 16 + m] = am[tl];
            aip[gtok + tl * 16 + m] = ai[tl];
        }
    }
    #pragma unroll
    for (int tl = 0; tl < 4; ++tl) {
        float* dst = hvp + (gtok + tl * 16 + m) * VDIM;
        *(f32x4*)(dst + 8 * q)     = hv0[tl];
        *(f32x4*)(dst + 8 * q + 4) = hv1[tl];
    }
}

// ---------------------------------------------------------------------------
// k_out: merge 16 partial splits -> softmax-normalize hv -> out = hv@Wpi^T+bpi.
// 512 blocks x 256 threads; 16 tokens/block.
// ---------------------------------------------------------------------------
__global__ __launch_bounds__(256) void k_out(const unsigned short* __restrict__ W,
                                             const float* __restrict__ mask,
                                             const float* __restrict__ bpi,
                                             const float* __restrict__ hvp,
                                             const float* __restrict__ lp,
                                             const float* __restrict__ amp,
                                             const int* __restrict__ aip,
                                             float* __restrict__ out,
                                             float* __restrict__ code_out) {
    __shared__ float invl[16];
    __shared__ __align__(16) unsigned short hvh[16][40];
    __shared__ __align__(16) unsigned short hvl[16][40];
    const unsigned short* Wpi_hi = W + OFS_WPI_HI;
    const unsigned short* Wpi_lo = W + OFS_WPI_LO;
    int tid = threadIdx.x;
    int tok0 = blockIdx.x * 16;
    const f32x4 zero4 = {0.f, 0.f, 0.f, 0.f};

    if (tid < 16) {
        int tk = tok0 + tid;
        float L = 0.f, A = -1e30f;
        int I = 0x7fffffff;
        #pragma unroll
        for (int sp = 0; sp < NSPLIT; ++sp) {
            size_t gi = (size_t)sp * NTOK + tk;
            L += lp[gi];
            float a2 = amp[gi];
            int   i2 = aip[gi];
            if (a2 > A || (a2 == A && i2 < I)) { A = a2; I = i2; }
        }
        bool on = (mask[tk] == 1.0f);
        code_out[tk] = on ? (float)I : 0.0f;
        invl[tid] = on ? (1.0f / L) : 0.0f;
    }
    __syncthreads();
    #pragma unroll
    for (int it = 0; it < 2; ++it) {
        int idx = it * 256 + tid;
        int t = idx >> 5, v = idx & 31;
        float x = 0.f;
        #pragma unroll
        for (int sp = 0; sp < NSPLIT; ++sp)
            x += hvp[((size_t)sp * NTOK + tok0 + t) * VDIM + v];
        x *= invl[t];
        unsigned short hb = f2bf(x);
        hvh[t][v] = hb;
        hvl[t][v] = f2bf(x - bf2f(hb));
    }
    __syncthreads();
    int w = tid >> 6, l = tid & 63, q = l >> 4, m = l & 15;
    short8 gh = *(const short8*)&hvh[m][q * 8];
    short8 gl = *(const short8*)&hvl[m][q * 8];
    #pragma unroll
    for (int dt = 0; dt < 16; ++dt) {
        int dbase = w * 256 + dt * 16;
        short8 Ah = *(const short8*)(Wpi_hi + (size_t)(dbase + m) * VDIM + q * 8);
        short8 Al = *(const short8*)(Wpi_lo + (size_t)(dbase + m) * VDIM + q * 8);
        f32x4 o = MFMA16(Al, gh, zero4);
        o = MFMA16(Ah, gl, o);
        o = MFMA16(Ah, gh, o);
        float4 bias = *(const float4*)(bpi + dbase + 4 * q);
        float4 r0 = make_float4(o[0] + bias.x, o[1] + bias.y,
                                o[2] + bias.z, o[3] + bias.w);
        *(float4*)(out + (size_t)(tok0 + m) * DIM + dbase + 4 * q) = r0;
    }
}

// ---------------------------------------------------------------------------
extern "C" void kernel_launch(void* const* d_in, const int* in_sizes, int n_in,
                              void* d_out, int out_size, void* d_ws, size_t ws_size,
                              hipStream_t stream) {
    const float* h    = (const float*)d_in[0];
    const float* mask = (const float*)d_in[1];
    const float* Wp   = (const float*)d_in[2];
    const float* bp   = (const float*)d_in[3];
    const float* Wpi  = (const float*)d_in[4];
    const float* bpi  = (const float*)d_in[5];
    const float* emb  = (const float*)d_in[6];
    float* out = (float*)d_out;

    unsigned short* W = (unsigned short*)d_ws;
    unsigned short* hp_hi = W + OFS_HP_HI;
    unsigned short* hp_lo = W + OFS_HP_LO;
    float* fbase = (float*)(W + F32_BASE);
    float* hvp = fbase + FOFS_HVP;
    float* lpp = fbase + FOFS_LP;
    float* ampp = fbase + FOFS_AMP;
    int*   aipp = (int*)(fbase + FOFS_AIP);

    float* code_out = out + (size_t)NTOK * DIM;
    float* loss_out = code_out + NTOK;

    hipLaunchKernelGGL(k_prep, dim3(96),   dim3(256), 0, stream, emb, Wp, Wpi, W, loss_out);
    hipLaunchKernelGGL(k_proj, dim3(512),  dim3(256), 0, stream, h, W, bp, hp_hi, hp_lo);
    hipLaunchKernelGGL(k_vq,   dim3(1024), dim3(128), 0, stream, W, hvp, lpp, ampp, aipp);
    hipLaunchKernelGGL(k_out,  dim3(512),  dim3(256), 0, stream, W, mask, bpi, hvp, lpp, ampp, aipp, out, code_out);
}

// Round 10
// 132.895 us; speedup vs baseline: 1.0639x; 1.0639x over previous
//
#include <hip/hip_runtime.h>
#include <hip/hip_bf16.h>
#include <math.h>

#define NTOK 8192     // B*L
#define DIM  1024     // D
#define VDIM 32       // V
#define KCODES 4096   // K

// hp is pre-scaled by 2*log2(e): score MFMA yields c*s, softmax weight = exp2(c*s) = e^{2s}.
#define SC 2.8853900817779268f

typedef __attribute__((ext_vector_type(8))) short short8;
typedef __attribute__((ext_vector_type(4))) float f32x4;

// MFMA16(A,B,C): D[row 4q+r = A-row][col m = B-row]; A-frag lane(q,m) holds
// A[m][k=q*8+j], B-frag lane(q,m) holds B[n=m][k=q*8+j]. (verified R2-R9)
#define MFMA16(A,B,C) __builtin_amdgcn_mfma_f32_16x16x32_bf16(A, B, C, 0, 0, 0)

__device__ __forceinline__ unsigned short f2bf(float x) {
    unsigned u = __builtin_bit_cast(unsigned, x);
    u += 0x7FFF + ((u >> 16) & 1);              // RTNE (finite inputs only)
    return (unsigned short)(u >> 16);
}
__device__ __forceinline__ float bf2f(unsigned short b) {
    unsigned u = ((unsigned)b) << 16;
    return __builtin_bit_cast(float, u);
}
__device__ __forceinline__ float fexp2(float x) {
#if __has_builtin(__builtin_amdgcn_exp2f)
    return __builtin_amdgcn_exp2f(x);
#else
    return __expf(0.6931471805599453f * x);
#endif
}

struct U4 { unsigned x, y, z, w; };

// split 8 fp32 -> bf16 hi/lo fragments (RTNE; element j of frag = p[j])
__device__ __forceinline__ void split8(const float* p, short8* H, short8* L) {
    unsigned hh[4], ll[4];
    #pragma unroll
    for (int i = 0; i < 4; ++i) {
        unsigned short a = f2bf(p[2 * i]);
        unsigned short b = f2bf(p[2 * i + 1]);
        hh[i] = (unsigned)a | ((unsigned)b << 16);
        unsigned short la = f2bf(p[2 * i] - bf2f(a));
        unsigned short lb = f2bf(p[2 * i + 1] - bf2f(b));
        ll[i] = (unsigned)la | ((unsigned)lb << 16);
    }
    U4 uh = {hh[0], hh[1], hh[2], hh[3]};
    U4 ul = {ll[0], ll[1], ll[2], ll[3]};
    *H = __builtin_bit_cast(short8, uh);
    *L = __builtin_bit_cast(short8, ul);
}

// pack 8 positive fp32 -> bf16 (round-half-up) via v_perm: 8 adds + 4 perms
__device__ __forceinline__ short8 pack8(const float* p) {
    unsigned u[8];
    #pragma unroll
    for (int j = 0; j < 8; ++j) u[j] = __builtin_bit_cast(unsigned, p[j]) + 0x8000u;
    U4 uh;
    uh.x = __builtin_amdgcn_perm(u[1], u[0], 0x07060302);
    uh.y = __builtin_amdgcn_perm(u[3], u[2], 0x07060302);
    uh.z = __builtin_amdgcn_perm(u[5], u[4], 0x07060302);
    uh.w = __builtin_amdgcn_perm(u[7], u[6], 0x07060302);
    return __builtin_bit_cast(short8, uh);
}

// LDS chunk swizzle for the E tile (row pad 40 u16 + XOR'd 16B chunk index):
// spreads the sigma-permuted b128 reads across bank groups.
__device__ __forceinline__ int lsw(int row, int j) {
    int s = ((row >> 1) ^ (row >> 3)) & 3;
    return row * 40 + ((j ^ s) * 8);
}

// ---------------------------------------------------------------------------
// ws layout: u16 region then f32 region
// ---------------------------------------------------------------------------
#define OFS_E_HI   0          // E  [4096][32]
#define OFS_E_LO   131072
#define OFS_ET_HI  262144     // Et [32][4096] (hi only; PV drops the lo term)
#define OFS_WP_HI  393216     // Wp [32][1024]
#define OFS_WP_LO  425984
#define OFS_WPI_HI 458752     // Wpi [1024][32]
#define OFS_WPI_LO 491520
#define OFS_HP_HI  524288     // hp  [8192][32] (scaled by SC)
#define OFS_HP_LO  786432
#define F32_BASE   1048576    // u16 units -> float* fbase
#define NSPLIT 8
#define FOFS_HVP 0            // [8][8192][32] fp32 partial hv
#define FOFS_LP  2097152      // [8][8192]
#define FOFS_AMP 2162688      // [8][8192]
#define FOFS_AIP 2228224      // [8][8192] (int)

// ---------------------------------------------------------------------------
// k_prep: normalize emb -> E hi/lo + Et hi (coalesced via LDS transpose);
// split Wp/Wpi; vq_loss = 0.
// ---------------------------------------------------------------------------
__global__ __launch_bounds__(256) void k_prep(const float* __restrict__ emb,
                                              const float* __restrict__ Wp,
                                              const float* __restrict__ Wpi,
                                              unsigned short* __restrict__ W,
                                              float* __restrict__ loss_out) {
    __shared__ __align__(16) unsigned short Th[32][72];
    int bid = blockIdx.x, tid = threadIdx.x;
    if (bid < 64) {                       // 64 codes per block
        int cb = bid * 64;
        int c = tid >> 2, s = tid & 3;    // code-local, v-quarter
        const float* src = emb + (size_t)(cb + c) * VDIM + s * 8;
        float4 a = *(const float4*)src;
        float4 b = *(const float4*)(src + 4);
        float ps = a.x*a.x + a.y*a.y + a.z*a.z + a.w*a.w
                 + b.x*b.x + b.y*b.y + b.z*b.z + b.w*b.w;
        ps += __shfl_xor(ps, 1);
        ps += __shfl_xor(ps, 2);
        float inv = 1.0f / sqrtf(ps);
        float vals[8] = {a.x*inv, a.y*inv, a.z*inv, a.w*inv,
                         b.x*inv, b.y*inv, b.z*inv, b.w*inv};
        short8 H, L;
        split8(vals, &H, &L);
        *(short8*)(W + OFS_E_HI + (size_t)(cb + c) * VDIM + s * 8) = H;
        *(short8*)(W + OFS_E_LO + (size_t)(cb + c) * VDIM + s * 8) = L;
        #pragma unroll
        for (int j = 0; j < 8; ++j) Th[s * 8 + j][c] = f2bf(vals[j]);
        __syncthreads();
        int row = tid >> 3, seg = tid & 7;
        *(short8*)(W + OFS_ET_HI + (size_t)row * KCODES + cb + seg * 8) =
            *(const short8*)&Th[row][seg * 8];
        if (bid == 0 && tid == 0) loss_out[0] = 0.0f;
    } else if (bid < 80) {                // Wp split: 16 blocks x 2048
        int i0 = (bid - 64) * 2048 + tid * 8;
        float4 a = *(const float4*)(Wp + i0);
        float4 b = *(const float4*)(Wp + i0 + 4);
        float vals[8] = {a.x, a.y, a.z, a.w, b.x, b.y, b.z, b.w};
        short8 H, L;
        split8(vals, &H, &L);
        *(short8*)(W + OFS_WP_HI + i0) = H;
        *(short8*)(W + OFS_WP_LO + i0) = L;
    } else {                              // Wpi split: 16 blocks x 2048
        int i0 = (bid - 80) * 2048 + tid * 8;
        float4 a = *(const float4*)(Wpi + i0);
        float4 b = *(const float4*)(Wpi + i0 + 4);
        float vals[8] = {a.x, a.y, a.z, a.w, b.x, b.y, b.z, b.w};
        short8 H, L;
        split8(vals, &H, &L);
        *(short8*)(W + OFS_WPI_HI + i0) = H;
        *(short8*)(W + OFS_WPI_LO + i0) = L;
    }
}

// ---------------------------------------------------------------------------
// k_proj: hp = h @ Wp^T + bp, L2-normalize, scale by SC, write bf16 hi/lo.
// 512 blocks x 256 threads (4 waves); 16 tokens/block; wave = 256-wide k-slice.
// ---------------------------------------------------------------------------
__global__ __launch_bounds__(256) void k_proj(const float* __restrict__ h,
                                              const unsigned short* __restrict__ W,
                                              const float* __restrict__ bp,
                                              unsigned short* __restrict__ hp_hi,
                                              unsigned short* __restrict__ hp_lo) {
    __shared__ __align__(16) float red[4][16][36];
    const unsigned short* Wp_hi = W + OFS_WP_HI;
    const unsigned short* Wp_lo = W + OFS_WP_LO;
    int tid = threadIdx.x;
    int w = tid >> 6, l = tid & 63, q = l >> 4, m = l & 15;
    int tok0 = blockIdx.x * 16;
    const f32x4 zero4 = {0.f, 0.f, 0.f, 0.f};
    f32x4 acc0 = zero4, acc1 = zero4;
    const float* hb = h + (size_t)(tok0 + m) * DIM + w * 256 + q * 8;
    const unsigned short* w0h = Wp_hi + (size_t)m * DIM + w * 256 + q * 8;
    const unsigned short* w0l = Wp_lo + (size_t)m * DIM + w * 256 + q * 8;
    const unsigned short* w1h = w0h + (size_t)16 * DIM;
    const unsigned short* w1l = w0l + (size_t)16 * DIM;
    #pragma unroll
    for (int c = 0; c < 8; ++c) {
        float4 a = *(const float4*)(hb + c * 32);
        float4 b = *(const float4*)(hb + c * 32 + 4);
        float va[8] = {a.x, a.y, a.z, a.w, b.x, b.y, b.z, b.w};
        short8 Bh, Bl;
        split8(va, &Bh, &Bl);
        short8 A0h = *(const short8*)(w0h + c * 32);
        short8 A0l = *(const short8*)(w0l + c * 32);
        short8 A1h = *(const short8*)(w1h + c * 32);
        short8 A1l = *(const short8*)(w1l + c * 32);
        acc0 = MFMA16(A0l, Bl, acc0); acc0 = MFMA16(A0l, Bh, acc0);
        acc0 = MFMA16(A0h, Bl, acc0); acc0 = MFMA16(A0h, Bh, acc0);
        acc1 = MFMA16(A1l, Bl, acc1); acc1 = MFMA16(A1l, Bh, acc1);
        acc1 = MFMA16(A1h, Bl, acc1); acc1 = MFMA16(A1h, Bh, acc1);
    }
    *(f32x4*)&red[w][m][4 * q]      = acc0;   // v = 4q+r, token m
    *(f32x4*)&red[w][m][16 + 4 * q] = acc1;
    __syncthreads();
    #pragma unroll
    for (int half = 0; half < 2; ++half) {
        int t = (tid >> 5) + half * 8, v = tid & 31;
        float s = bp[v];
        #pragma unroll
        for (int j = 0; j < 4; ++j) s += red[j][t][v];
        float sq = s * s;
        #pragma unroll
        for (int off = 1; off < 32; off <<= 1) sq += __shfl_xor(sq, off);
        float nv = s * (SC / sqrtf(sq));
        unsigned short hb2 = f2bf(nv);
        size_t idx = (size_t)(tok0 + t) * VDIM + v;
        hp_hi[idx] = hb2;
        hp_lo[idx] = f2bf(nv - bf2f(hb2));
    }
}

// ---------------------------------------------------------------------------
// k_vq: scores (3-product split fp32) -> exp2 -> argmax -> P@E^T (hi-only).
// 512 blocks x 256 threads (4 waves, launch_bounds(256,2): 2 blocks/CU).
// block = 128 tokens x 512-code slice (sp = bid&7); wave = TWO independent
// 16-token tiles (ILP-2) sharing every E/Et fragment -> 16 MFMAs per
// fragment-load set. E hi/lo double-buffered through LDS in 64-code tiles;
// Et register-prefetched one chunk ahead. Per tile-chunk the exp2->pack->PV
// MFMAs issue BEFORE the argmax/sum VALU so that bookkeeping executes in the
// MFMA shadow (R10 reorder).
// ---------------------------------------------------------------------------
__global__ __launch_bounds__(256, 2) void k_vq(const unsigned short* __restrict__ W,
                                               float* __restrict__ hvp,
                                               float* __restrict__ lp,
                                               float* __restrict__ amp,
                                               int* __restrict__ aip) {
    __shared__ __align__(16) unsigned short Eh[2][64 * 40];   // 20 KB total
    __shared__ __align__(16) unsigned short El[2][64 * 40];

    const unsigned short* E_hi  = W + OFS_E_HI;
    const unsigned short* E_lo  = W + OFS_E_LO;
    const unsigned short* Et_hi = W + OFS_ET_HI;
    const unsigned short* hp_hi = W + OFS_HP_HI;
    const unsigned short* hp_lo = W + OFS_HP_LO;

    int tid = threadIdx.x;
    int w = tid >> 6, l = tid & 63, q = l >> 4, m = l & 15;
    int tg = blockIdx.x >> 3, sp = blockIdx.x & 7;
    int tok0 = tg * 128 + w * 32;            // wave's 32 tokens (2 tiles)
    int cb0 = sp * 512;
    int sig = ((m & 12) << 1) | (m & 3);     // sigma(m) = 8*(m>>2)+(m&3)
    const f32x4 zero4 = {0.f, 0.f, 0.f, 0.f};

    // staging: 64 codes * 4 chunk16 = 256 16B-chunks; thread -> 1 hi + 1 lo
    int cs = tid >> 2, js = tid & 3;
    int lds_off = lsw(cs, js);
    size_t gs = (size_t)cs * VDIM + js * 8;

    size_t h0 = (size_t)(tok0 + m) * VDIM + q * 8;
    short8 hph0 = *(const short8*)(hp_hi + h0);
    short8 hpl0 = *(const short8*)(hp_lo + h0);
    short8 hph1 = *(const short8*)(hp_hi + h0 + 16 * VDIM);
    short8 hpl1 = *(const short8*)(hp_lo + h0 + 16 * VDIM);

    // prologue: stage tile 0 into buf 0
    {
        size_t tb = (size_t)cb0 * VDIM;
        short8 a = *(const short8*)(E_hi + tb + gs);
        short8 b = *(const short8*)(E_lo + tb + gs);
        *(short8*)&Eh[0][lds_off] = a;
        *(short8*)&El[0][lds_off] = b;
    }
    __syncthreads();

    f32x4 hv00 = zero4, hv01 = zero4, hv10 = zero4, hv11 = zero4;
    float ls0 = 0.f, ls1 = 0.f, am0 = -1e30f, am1 = -1e30f;
    int ai0 = 0, ai1 = 0;

    // Et prefetch for chunk 0
    size_t tA = (size_t)sig * KCODES + cb0 + q * 8;
    short8 T0h = *(const short8*)(Et_hi + tA);
    short8 T1h = *(const short8*)(Et_hi + tA + (size_t)4 * KCODES);

    #pragma unroll 1
    for (int t = 0; t < 8; ++t) {            // 8 LDS tiles of 64 codes
        int buf = t & 1;
        short8 sa, sb;
        if (t < 7) {                         // issue next tile's staging loads
            size_t tb = (size_t)(cb0 + (t + 1) * 64) * VDIM;
            sa = *(const short8*)(E_hi + tb + gs);
            sb = *(const short8*)(E_lo + tb + gs);
        }
        #pragma unroll
        for (int cc = 0; cc < 2; ++cc) {     // 2 chunks of 32 codes
            int cbase = cb0 + t * 64 + cc * 32;
            // prefetch Et for next chunk (tail reads in-bounds unused ws)
            size_t tN = (size_t)sig * KCODES + (cbase + 32) + q * 8;
            short8 nT0h = *(const short8*)(Et_hi + tN);
            short8 nT1h = *(const short8*)(Et_hi + tN + (size_t)4 * KCODES);
            // E fragments from LDS (swizzled) — shared by both token tiles
            int r0 = cc * 32 + sig;
            short8 E0h = *(const short8*)&Eh[buf][lsw(r0, q)];
            short8 E0l = *(const short8*)&El[buf][lsw(r0, q)];
            short8 E1h = *(const short8*)&Eh[buf][lsw(r0 + 4, q)];
            short8 E1l = *(const short8*)&El[buf][lsw(r0 + 4, q)];
            int lbase = cbase + 8 * q;       // lane's codes: lbase+j, j=0..7

            // ---- token tile 0 ----
            {
                f32x4 s0 = MFMA16(E0h, hpl0, zero4);
                s0 = MFMA16(E0l, hph0, s0);
                s0 = MFMA16(E0h, hph0, s0);
                f32x4 s1 = MFMA16(E1h, hpl0, zero4);
                s1 = MFMA16(E1l, hph0, s1);
                s1 = MFMA16(E1h, hph0, s1);
                float p[8];
                #pragma unroll
                for (int r = 0; r < 4; ++r) {
                    p[r]     = fexp2(s0[r]);
                    p[4 + r] = fexp2(s1[r]);
                }
                short8 Ph = pack8(p);        // PV issues first (R10 reorder)
                hv00 = MFMA16(T0h, Ph, hv00);    // v = 8q+r,   token m
                hv01 = MFMA16(T1h, Ph, hv01);    // v = 8q+4+r, token m
                #pragma unroll
                for (int r = 0; r < 4; ++r) {    // bookkeeping in MFMA shadow
                    float sv = s0[r];
                    if (sv > am0) { am0 = sv; ai0 = lbase + r; }
                    sv = s1[r];
                    if (sv > am0) { am0 = sv; ai0 = lbase + 4 + r; }
                }
                ls0 += ((p[0] + p[1]) + (p[2] + p[3])) + ((p[4] + p[5]) + (p[6] + p[7]));
            }
            // ---- token tile 1 ----
            {
                f32x4 s0 = MFMA16(E0h, hpl1, zero4);
                s0 = MFMA16(E0l, hph1, s0);
                s0 = MFMA16(E0h, hph1, s0);
                f32x4 s1 = MFMA16(E1h, hpl1, zero4);
                s1 = MFMA16(E1l, hph1, s1);
                s1 = MFMA16(E1h, hph1, s1);
                float p[8];
                #pragma unroll
                for (int r = 0; r < 4; ++r) {
                    p[r]     = fexp2(s0[r]);
                    p[4 + r] = fexp2(s1[r]);
                }
                short8 Ph = pack8(p);
                hv10 = MFMA16(T0h, Ph, hv10);
                hv11 = MFMA16(T1h, Ph, hv11);
                #pragma unroll
                for (int r = 0; r < 4; ++r) {
                    float sv = s0[r];
                    if (sv > am1) { am1 = sv; ai1 = lbase + r; }
                    sv = s1[r];
                    if (sv > am1) { am1 = sv; ai1 = lbase + 4 + r; }
                }
                ls1 += ((p[0] + p[1]) + (p[2] + p[3])) + ((p[4] + p[5]) + (p[6] + p[7]));
            }
            T0h = nT0h; T1h = nT1h;
        }
        if (t < 7) {
            int nb = buf ^ 1;
            *(short8*)&Eh[nb][lds_off] = sa;
            *(short8*)&El[nb][lds_off] = sb;
            __syncthreads();
        }
    }

    // cross-q reduce (lane bits 4,5 share token column m)
    #pragma unroll
    for (int off = 16; off <= 32; off <<= 1) {
        ls0 += __shfl_xor(ls0, off);
        float a2 = __shfl_xor(am0, off);
        int   i2 = __shfl_xor(ai0, off);
        if (a2 > am0 || (a2 == am0 && i2 < ai0)) { am0 = a2; ai0 = i2; }
        ls1 += __shfl_xor(ls1, off);
        a2 = __shfl_xor(am1, off);
        i2 = __shfl_xor(ai1, off);
        if (a2 > am1 || (a2 == am1 && i2 < ai1)) { am1 = a2; ai1 = i2; }
    }
    size_t gtok = (size_t)sp * NTOK + tok0;
    if (q == 0) {
        lp[gtok + m] = ls0;      amp[gtok + m] = am0;      aip[gtok + m] = ai0;
        lp[gtok + 16 + m] = ls1; amp[gtok + 16 + m] = am1; aip[gtok + 16 + m] = ai1;
    }
    float* dst0 = hvp + (gtok + m) * VDIM;
    *(f32x4*)(dst0 + 8 * q)     = hv00;
    *(f32x4*)(dst0 + 8 * q + 4) = hv01;
    float* dst1 = hvp + (gtok + 16 + m) * VDIM;
    *(f32x4*)(dst1 + 8 * q)     = hv10;
    *(f32x4*)(dst1 + 8 * q + 4) = hv11;
}

// ---------------------------------------------------------------------------
// k_out: merge 8 partial splits -> softmax-normalize hv -> out = hv@Wpi^T+bpi.
// 512 blocks x 256 threads; 16 tokens/block. Merge loads parallelized over
// 128 threads (R10).
// ---------------------------------------------------------------------------
__global__ __launch_bounds__(256) void k_out(const unsigned short* __restrict__ W,
                                             const float* __restrict__ mask,
                                             const float* __restrict__ bpi,
                                             const float* __restrict__ hvp,
                                             const float* __restrict__ lp,
                                             const float* __restrict__ amp,
                                             const int* __restrict__ aip,
                                             float* __restrict__ out,
                                             float* __restrict__ code_out) {
    __shared__ float invl[16];
    __shared__ float lred[16][9];
    __shared__ float amred[16][9];
    __shared__ int   aired[16][9];
    __shared__ __align__(16) unsigned short hvh[16][40];
    __shared__ __align__(16) unsigned short hvl[16][40];
    const unsigned short* Wpi_hi = W + OFS_WPI_HI;
    const unsigned short* Wpi_lo = W + OFS_WPI_LO;
    int tid = threadIdx.x;
    int tok0 = blockIdx.x * 16;
    const f32x4 zero4 = {0.f, 0.f, 0.f, 0.f};

    if (tid < 128) {                      // parallel merge loads
        int t = tid >> 3, s = tid & 7;
        size_t gi = (size_t)s * NTOK + tok0 + t;
        lred[t][s]  = lp[gi];
        amred[t][s] = amp[gi];
        aired[t][s] = aip[gi];
    }
    __syncthreads();
    if (tid < 16) {
        float L = 0.f, A = -1e30f;
        int I = 0x7fffffff;
        #pragma unroll
        for (int s = 0; s < NSPLIT; ++s) {
            L += lred[tid][s];
            float a2 = amred[tid][s];
            int   i2 = aired[tid][s];
            if (a2 > A || (a2 == A && i2 < I)) { A = a2; I = i2; }
        }
        bool on = (mask[tok0 + tid] == 1.0f);
        code_out[tok0 + tid] = on ? (float)I : 0.0f;
        invl[tid] = on ? (1.0f / L) : 0.0f;
    }
    __syncthreads();
    #pragma unroll
    for (int it = 0; it < 2; ++it) {
        int idx = it * 256 + tid;
        int t = idx >> 5, v = idx & 31;
        float x = 0.f;
        #pragma unroll
        for (int sp = 0; sp < NSPLIT; ++sp)
            x += hvp[((size_t)sp * NTOK + tok0 + t) * VDIM + v];
        x *= invl[t];
        unsigned short hb = f2bf(x);
        hvh[t][v] = hb;
        hvl[t][v] = f2bf(x - bf2f(hb));
    }
    __syncthreads();
    int w = tid >> 6, l = tid & 63, q = l >> 4, m = l & 15;
    short8 gh = *(const short8*)&hvh[m][q * 8];
    short8 gl = *(const short8*)&hvl[m][q * 8];
    #pragma unroll
    for (int dt = 0; dt < 16; ++dt) {
        int dbase = w * 256 + dt * 16;
        short8 Ah = *(const short8*)(Wpi_hi + (size_t)(dbase + m) * VDIM + q * 8);
        short8 Al = *(const short8*)(Wpi_lo + (size_t)(dbase + m) * VDIM + q * 8);
        f32x4 o = MFMA16(Al, gh, zero4);
        o = MFMA16(Ah, gl, o);
        o = MFMA16(Ah, gh, o);
        float4 bias = *(const float4*)(bpi + dbase + 4 * q);
        float4 r0 = make_float4(o[0] + bias.x, o[1] + bias.y,
                                o[2] + bias.z, o[3] + bias.w);
        *(float4*)(out + (size_t)(tok0 + m) * DIM + dbase + 4 * q) = r0;
    }
}

// ---------------------------------------------------------------------------
extern "C" void kernel_launch(void* const* d_in, const int* in_sizes, int n_in,
                              void* d_out, int out_size, void* d_ws, size_t ws_size,
                              hipStream_t stream) {
    const float* h    = (const float*)d_in[0];
    const float* mask = (const float*)d_in[1];
    const float* Wp   = (const float*)d_in[2];
    const float* bp   = (const float*)d_in[3];
    const float* Wpi  = (const float*)d_in[4];
    const float* bpi  = (const float*)d_in[5];
    const float* emb  = (const float*)d_in[6];
    float* out = (float*)d_out;

    unsigned short* W = (unsigned short*)d_ws;
    unsigned short* hp_hi = W + OFS_HP_HI;
    unsigned short* hp_lo = W + OFS_HP_LO;
    float* fbase = (float*)(W + F32_BASE);
    float* hvp = fbase + FOFS_HVP;
    float* lpp = fbase + FOFS_LP;
    float* ampp = fbase + FOFS_AMP;
    int*   aipp = (int*)(fbase + FOFS_AIP);

    float* code_out = out + (size_t)NTOK * DIM;
    float* loss_out = code_out + NTOK;

    hipLaunchKernelGGL(k_prep, dim3(96),  dim3(256), 0, stream, emb, Wp, Wpi, W, loss_out);
    hipLaunchKernelGGL(k_proj, dim3(512), dim3(256), 0, stream, h, W, bp, hp_hi, hp_lo);
    hipLaunchKernelGGL(k_vq,   dim3(512), dim3(256), 0, stream, W, hvp, lpp, ampp, aipp);
    hipLaunchKernelGGL(k_out,  dim3(512), dim3(256), 0, stream, W, mask, bpi, hvp, lpp, ampp, aipp, out, code_out);
}